// Round 1
// baseline (84.037 us; speedup 1.0000x reference)
//
#include <hip/hip_runtime.h>

// N=4096, PAIR=2, M=64, D=128, O=128, R=2, MAX_DEG=32
// h = relu(x @ (d*Wsum + W0) + (d*bsum + b0));  out[n] = h0 @ h1^T
//
// Pre-kernel: build W_eff[d] for d=0..31 in bf16 MFMA-B-fragment layout:
//   wfrag[((d*8 + ct)*4 + ks)*64 + lane][j]  = W_eff[d][k][o]
//   with k = ks*32 + (lane>>4)*8 + j, o = ct*16 + (lane&15)
// plus c_all[d][o] = d*bsum[o] + b0[o]  (fp32).
// Main kernel: 1 block per node, 4 waves; GEMM1 -> h in swizzled LDS -> GEMM2.

typedef __attribute__((ext_vector_type(8))) short bf16x8;
typedef __attribute__((ext_vector_type(4))) float f32x4;

__device__ __forceinline__ unsigned short f2bf(float f) {
    union { float f; unsigned u; } v; v.f = f;
    unsigned r = (v.u + 0x7fffu + ((v.u >> 16) & 1u)) >> 16;
    return (unsigned short)r;
}

__global__ __launch_bounds__(256) void build_weights(
    const float* __restrict__ W_r,  // [2,128,128]
    const float* __restrict__ b_r,  // [2,128]
    const float* __restrict__ W0,   // [128,128]
    const float* __restrict__ b0,   // [128]
    unsigned short* __restrict__ wfrag,  // [32*8*4*64*8]
    float* __restrict__ call)            // [32*128]
{
    int t = blockIdx.x * blockDim.x + threadIdx.x;   // 0..65535
    int lane = t & 63;
    int ks = (t >> 6) & 3;
    int ct = (t >> 8) & 7;
    int d  = (t >> 11) & 31;
    int o = ct * 16 + (lane & 15);
    int kbase = ks * 32 + (lane >> 4) * 8;
    unsigned short* dst = wfrag + (size_t)t * 8;
#pragma unroll
    for (int j = 0; j < 8; ++j) {
        int k = kbase + j;
        float wsum = W_r[k * 128 + o] + W_r[128 * 128 + k * 128 + o];
        float w = (float)d * wsum + W0[k * 128 + o];
        dst[j] = f2bf(w);
    }
    if (t < 32 * 128) {
        int dd = t >> 7, oo = t & 127;
        call[t] = (float)dd * (b_r[oo] + b_r[128 + oo]) + b0[oo];
    }
}

__global__ __launch_bounds__(256) void edge_kernel(
    const float* __restrict__ x,    // [N,2,64,128] f32
    const int* __restrict__ deg,    // [N]
    const unsigned short* __restrict__ wfrag,
    const float* __restrict__ call,
    float* __restrict__ out)        // [N,64,64] f32
{
    // h tile, bf16, XOR-swizzled: byte(row,col) = row*256 + (((col>>3)^(row&7))<<4) + (col&7)*2
    __shared__ unsigned short hlds[128 * 128];  // 32 KB

    const int n = blockIdx.x;
    const int tid = threadIdx.x;
    const int wave = tid >> 6;
    const int lane = tid & 63;
    const int l15 = lane & 15;
    const int lhi = lane >> 4;      // 0..3
    const int d = deg[n];

    const float* xn = x + (size_t)n * (2 * 64 * 128);
    const unsigned short* wf = wfrag + (size_t)d * (8 * 4 * 64 * 8);
    const float* cd = call + d * 128;

    // ---- load A fragments (this wave's 32 rows of X), fp32 -> bf16 ----
    const int rbase = wave * 32;
    bf16x8 afrag[2][4];
#pragma unroll
    for (int rt = 0; rt < 2; ++rt) {
        const float* rowp = xn + (size_t)(rbase + rt * 16 + l15) * 128;
#pragma unroll
        for (int ks = 0; ks < 4; ++ks) {
            const float4* p = (const float4*)(rowp + ks * 32 + lhi * 8);
            float4 a0 = p[0];
            float4 a1 = p[1];
            bf16x8 f;
            f[0] = (short)f2bf(a0.x); f[1] = (short)f2bf(a0.y);
            f[2] = (short)f2bf(a0.z); f[3] = (short)f2bf(a0.w);
            f[4] = (short)f2bf(a1.x); f[5] = (short)f2bf(a1.y);
            f[6] = (short)f2bf(a1.z); f[7] = (short)f2bf(a1.w);
            afrag[rt][ks] = f;
        }
    }

    // ---- GEMM1: pre = X @ W_eff[d]; fuse bias+relu, h -> LDS (bf16, swizzled) ----
#pragma unroll
    for (int ct = 0; ct < 8; ++ct) {
        bf16x8 bfrag[4];
#pragma unroll
        for (int ks = 0; ks < 4; ++ks)
            bfrag[ks] = *(const bf16x8*)(wf + ((size_t)(ct * 4 + ks) * 64 + lane) * 8);
        float cc = cd[ct * 16 + l15];
#pragma unroll
        for (int rt = 0; rt < 2; ++rt) {
            f32x4 acc = {0.f, 0.f, 0.f, 0.f};
#pragma unroll
            for (int ks = 0; ks < 4; ++ks)
                acc = __builtin_amdgcn_mfma_f32_16x16x32_bf16(afrag[rt][ks], bfrag[ks], acc, 0, 0, 0);
#pragma unroll
            for (int r = 0; r < 4; ++r) {
                int row = rbase + rt * 16 + lhi * 4 + r;
                int col = ct * 16 + l15;
                float hv = acc[r] + cc;
                hv = hv > 0.f ? hv : 0.f;
                int byteoff = row * 256 + ((((col >> 3) ^ (row & 7)) << 4)) + ((col & 7) << 1);
                hlds[byteoff >> 1] = f2bf(hv);
            }
        }
    }
    __syncthreads();

    // ---- GEMM2: out[n] = h0 @ h1^T ; wave w owns out rows 16w..16w+15 ----
    bf16x8 a2[4];
    {
        int row = wave * 16 + l15;          // row of h0
#pragma unroll
        for (int ks = 0; ks < 4; ++ks) {
            int chunk = ((ks * 4 + lhi) ^ (row & 7));
            a2[ks] = *(const bf16x8*)(hlds + ((row * 256 + chunk * 16) >> 1));
        }
    }
    float* outn = out + (size_t)n * 4096;
#pragma unroll
    for (int ct = 0; ct < 4; ++ct) {
        f32x4 acc = {0.f, 0.f, 0.f, 0.f};
        int row = 64 + ct * 16 + l15;       // row of h1 (= out col)
#pragma unroll
        for (int ks = 0; ks < 4; ++ks) {
            int chunk = ((ks * 4 + lhi) ^ (row & 7));
            bf16x8 b2 = *(const bf16x8*)(hlds + ((row * 256 + chunk * 16) >> 1));
            acc = __builtin_amdgcn_mfma_f32_16x16x32_bf16(a2[ks], b2, acc, 0, 0, 0);
        }
#pragma unroll
        for (int r = 0; r < 4; ++r) {
            int orow = wave * 16 + lhi * 4 + r;
            outn[orow * 64 + ct * 16 + l15] = acc[r];
        }
    }
}

extern "C" void kernel_launch(void* const* d_in, const int* in_sizes, int n_in,
                              void* d_out, int out_size, void* d_ws, size_t ws_size,
                              hipStream_t stream) {
    const float* x   = (const float*)d_in[0];   // node_features [4096,2,64,128]
    const int*   deg = (const int*)d_in[1];     // [4096]
    const float* W_r = (const float*)d_in[2];   // [2,128,128]
    const float* b_r = (const float*)d_in[3];   // [2,128]
    const float* W0  = (const float*)d_in[4];   // [128,128]
    const float* b0  = (const float*)d_in[5];   // [128]
    float* out = (float*)d_out;                 // [4096,64,64]

    unsigned short* wfrag = (unsigned short*)d_ws;                    // 1 MB
    float* call = (float*)((unsigned short*)d_ws + 32 * 8 * 4 * 64 * 8); // +16 KB

    build_weights<<<256, 256, 0, stream>>>(W_r, b_r, W0, b0, wfrag, call);
    edge_kernel<<<4096, 256, 0, stream>>>(x, deg, wfrag, call, out);
}